// Round 1
// baseline (665.218 us; speedup 1.0000x reference)
//
#include <hip/hip_runtime.h>
#include <hip/hip_bf16.h>
#include <math.h>

#define NROWS 16384
#define HID 64

typedef __attribute__((ext_vector_type(8))) __bf16 bf16x8;
typedef __attribute__((ext_vector_type(4))) float f32x4;

__device__ inline f32x4 mfma16(bf16x8 a, bf16x8 b, f32x4 c) {
    return __builtin_amdgcn_mfma_f32_16x16x32_bf16(a, b, c, 0, 0, 0);
}

__device__ inline void split8(const float4 v0, const float4 v1, bf16x8& h, bf16x8& l) {
    float f[8] = {v0.x, v0.y, v0.z, v0.w, v1.x, v1.y, v1.z, v1.w};
#pragma unroll
    for (int j = 0; j < 8; ++j) {
        __bf16 hh = (__bf16)f[j];
        h[j] = hh;
        l[j] = (__bf16)(f[j] - (float)hh);
    }
}

// ---------------------------------------------------------------------------
// pack_b: x [16384,64] fp32 row-major  ->  MFMA B-fragment-ordered bf16 hi/lo.
// Packed index: (((kb*4 + t)*64 + lane)*8 + j)
//   holds x[kb*32 + (lane>>4)*8 + j][t*16 + (lane&15)]
// so the consumer does one contiguous 16B load per lane (coalesced 1KB/wave).
// ---------------------------------------------------------------------------
__global__ __launch_bounds__(256) void pack_b(const float* __restrict__ x,
                                              __bf16* __restrict__ hi,
                                              __bf16* __restrict__ lo) {
    __shared__ float tile[32 * 64];
    const int kb = blockIdx.x;  // 0..511, 32 k-rows each
    const f32x4* src = (const f32x4*)(x + (size_t)kb * 32 * 64);
    f32x4* dst = (f32x4*)tile;
    dst[threadIdx.x] = src[threadIdx.x];
    dst[threadIdx.x + 256] = src[threadIdx.x + 256];
    __syncthreads();
    const int t = threadIdx.x >> 6;    // n-tile 0..3
    const int l = threadIdx.x & 63;    // consumer lane
    const int col = (t << 4) + (l & 15);
    const int krow = (l >> 4) * 8;
    bf16x8 h8, l8;
#pragma unroll
    for (int j = 0; j < 8; ++j) {
        float v = tile[(krow + j) * 64 + col];
        __bf16 hh = (__bf16)v;
        h8[j] = hh;
        l8[j] = (__bf16)(v - (float)hh);
    }
    const size_t base = (((size_t)kb * 4 + t) * 64 + l) * 8;
    *(bf16x8*)(hi + base) = h8;
    *(bf16x8*)(lo + base) = l8;
}

// ---------------------------------------------------------------------------
// gemm_agg: agg = adj @ x  via bf16 hi/lo split MFMA (3 MFMAs per tile-pair).
// Block = 4 waves. Each wave: 32 rows (2 row-groups of 16) x 64 cols, K/4.
// A fragments loaded straight from global fp32 (16 rows x 128B contiguous per
// k-step) and split in registers. Cross-wave K-reduction through LDS.
// ---------------------------------------------------------------------------
__global__ __launch_bounds__(256, 2) void gemm_agg(const float* __restrict__ adj,
                                                   const __bf16* __restrict__ Bhi,
                                                   const __bf16* __restrict__ Blo,
                                                   float* __restrict__ agg) {
    __shared__ float red[4][32][64];  // 32 KB

    const int lane = threadIdx.x & 63;
    const int wv = threadIdx.x >> 6;  // 0..3 : K-chunk owner
    const int rbase = blockIdx.x * 32;
    const int rq = lane & 15;   // row within 16-row group
    const int kq = lane >> 4;   // k-quarter 0..3

    f32x4 acc[2][4];
#pragma unroll
    for (int g = 0; g < 2; ++g)
#pragma unroll
        for (int t = 0; t < 4; ++t) acc[g][t] = f32x4{0.f, 0.f, 0.f, 0.f};

    const float* a0p = adj + (size_t)(rbase + rq) * NROWS + kq * 8;
    const float* a1p = a0p + (size_t)16 * NROWS;
    const int k0 = wv * (NROWS / 4);

    for (int kk = k0; kk < k0 + NROWS / 4; kk += 32) {
        // B fragments (L2-resident packed bf16), 8 x 16B coalesced loads
        const size_t bb = ((size_t)(kk >> 5) * 4) * 512 + (size_t)lane * 8;
        bf16x8 bh[4], bl[4];
#pragma unroll
        for (int t = 0; t < 4; ++t) {
            bh[t] = *(const bf16x8*)(Bhi + bb + (size_t)t * 512);
            bl[t] = *(const bf16x8*)(Blo + bb + (size_t)t * 512);
        }
        // A: 8 fp32 per lane per row-group, contiguous 32B
        float4 v0 = *(const float4*)(a0p + kk);
        float4 v1 = *(const float4*)(a0p + kk + 4);
        float4 w0 = *(const float4*)(a1p + kk);
        float4 w1 = *(const float4*)(a1p + kk + 4);
        bf16x8 ah0, al0, ah1, al1;
        split8(v0, v1, ah0, al0);
        split8(w0, w1, ah1, al1);

#pragma unroll
        for (int t = 0; t < 4; ++t) {
            acc[0][t] = mfma16(ah0, bh[t], acc[0][t]);
            acc[0][t] = mfma16(ah0, bl[t], acc[0][t]);
            acc[0][t] = mfma16(al0, bh[t], acc[0][t]);
            acc[1][t] = mfma16(ah1, bh[t], acc[1][t]);
            acc[1][t] = mfma16(ah1, bl[t], acc[1][t]);
            acc[1][t] = mfma16(al1, bh[t], acc[1][t]);
        }
    }

    // C/D layout: col = lane&15, row = (lane>>4)*4 + reg   [m89-verified]
#pragma unroll
    for (int g = 0; g < 2; ++g)
#pragma unroll
        for (int t = 0; t < 4; ++t)
#pragma unroll
            for (int r = 0; r < 4; ++r)
                red[wv][g * 16 + kq * 4 + r][t * 16 + (lane & 15)] = acc[g][t][r];
    __syncthreads();

    // 2048 floats / 256 threads = 8 each; sum the 4 K-chunks, write out
    const int row = threadIdx.x >> 3;
    const int c0 = (threadIdx.x & 7) * 8;
    f32x4 s0 = f32x4{0.f, 0.f, 0.f, 0.f};
    f32x4 s1 = f32x4{0.f, 0.f, 0.f, 0.f};
#pragma unroll
    for (int w = 0; w < 4; ++w) {
        s0 += *(const f32x4*)&red[w][row][c0];
        s1 += *(const f32x4*)&red[w][row][c0 + 4];
    }
    f32x4* outp = (f32x4*)(agg + (size_t)(rbase + row) * 64 + c0);
    outp[0] = s0;
    outp[1] = s1;
}

// ---------------------------------------------------------------------------
// dense_tanh: x_out[r,h] = tanh( [agg_r | x_r] @ W ),  W is [128,64] in LDS.
// lane = output column h; concat-row values broadcast via __shfl.
// ---------------------------------------------------------------------------
__global__ __launch_bounds__(256) void dense_tanh(const float* __restrict__ agg,
                                                  const float* __restrict__ xin,
                                                  const float* __restrict__ W,
                                                  float* __restrict__ xout) {
    __shared__ float wsm[128 * 64];  // 32 KB
    const f32x4* wsrc = (const f32x4*)W;
    f32x4* wdst = (f32x4*)wsm;
#pragma unroll
    for (int i = 0; i < 8; ++i) wdst[threadIdx.x + 256 * i] = wsrc[threadIdx.x + 256 * i];
    __syncthreads();

    const int lane = threadIdx.x & 63;
    const int wv = threadIdx.x >> 6;
    const int r0 = blockIdx.x * 32 + wv * 8;
#pragma unroll 2
    for (int i = 0; i < 8; ++i) {
        const int r = r0 + i;
        const float av = agg[(size_t)r * 64 + lane];
        const float xv = xin[(size_t)r * 64 + lane];
        float z = 0.f;
#pragma unroll
        for (int j = 0; j < 64; ++j) z += __shfl(av, j) * wsm[j * 64 + lane];
#pragma unroll
        for (int j = 0; j < 64; ++j) z += __shfl(xv, j) * wsm[(64 + j) * 64 + lane];
        xout[(size_t)r * 64 + lane] = tanhf(z);
    }
}

extern "C" void kernel_launch(void* const* d_in, const int* in_sizes, int n_in,
                              void* d_out, int out_size, void* d_ws, size_t ws_size,
                              hipStream_t stream) {
    const float* x0 = (const float*)d_in[0];   // user_embs [16384,64]
    const float* adj = (const float*)d_in[1];  // adj [16384,16384]
    const float* W = (const float*)d_in[2];    // W [2,128,64]
    float* out = (float*)d_out;

    char* ws = (char*)d_ws;
    __bf16* Bhi = (__bf16*)(ws);                      // 2 MB
    __bf16* Blo = (__bf16*)(ws + (2u << 20));         // 2 MB
    float* agg = (float*)(ws + (4u << 20));           // 4 MB
    float* x1 = (float*)(ws + (8u << 20));            // 4 MB

    // hop 0
    pack_b<<<512, 256, 0, stream>>>(x0, Bhi, Blo);
    gemm_agg<<<512, 256, 0, stream>>>(adj, Bhi, Blo, agg);
    dense_tanh<<<512, 256, 0, stream>>>(agg, x0, W, x1);
    // hop 1
    pack_b<<<512, 256, 0, stream>>>(x1, Bhi, Blo);
    gemm_agg<<<512, 256, 0, stream>>>(adj, Bhi, Blo, agg);
    dense_tanh<<<512, 256, 0, stream>>>(agg, x1, W + 128 * 64, out);
}